// Round 10
// baseline (451.975 us; speedup 1.0000x reference)
//
#include <hip/hip_runtime.h>
#include <stdint.h>

// ---- problem constants (from setup_inputs) ----
static constexpr int NV   = 80000;    // voxels per scale
static constexpr int NPT  = 240000;   // points N
static constexpr int NIMG = 60000;    // B*M image-projected points
static constexpr int Hh   = 64;
static constexpr int Cc   = 20;
static constexpr int NPp  = 120000;   // N per batch
static constexpr int Mm   = 30000;
static constexpr int NB     = 8192;   // error-histogram bins (top-15 float bits)
static constexpr int NCH    = 16;     // chunks per class in hist kernel
static constexpr int NBLK_GA = (NIMG + 63) / 64;   // 938 gemm_att blocks
#define BN_EPS 1e-5f

using bf16x8 = __attribute__((ext_vector_type(8))) short;
using f32x4  = __attribute__((ext_vector_type(4))) float;

// ================= small helpers =================
__device__ __forceinline__ float waveReduce(float v) {
  #pragma unroll
  for (int o = 32; o > 0; o >>= 1) v += __shfl_down(v, o);
  return v;
}
__device__ __forceinline__ int waveReduceI(int v) {
  #pragma unroll
  for (int o = 32; o > 0; o >>= 1) v += __shfl_down(v, o);
  return v;
}
__device__ __forceinline__ short f2bf(float f) {   // RNE fp32 -> bf16
  uint32_t u = __float_as_uint(f);
  return (short)((u + 0x7FFFu + ((u >> 16) & 1u)) >> 16);
}
__device__ __forceinline__ float bf2f(uint32_t h) { return __uint_as_float(h << 16); }
__device__ __forceinline__ uint32_t pk2(float a, float b) {
  return ((uint32_t)(uint16_t)f2bf(a)) | ((uint32_t)(uint16_t)f2bf(b) << 16);
}

// ============ voxel vote (+ gather-index fused, same ci input) ============
__global__ void k_counts_idx(const int* __restrict__ ci, const int* __restrict__ labels,
                             int* __restrict__ counts,
                             const int* __restrict__ p2img, int* __restrict__ idx) {
  int i = blockIdx.x * blockDim.x + threadIdx.x;
  if (i < NIMG) {
    int b = (i >= Mm) ? 1 : 0;               // B=2, contiguous batch blocks
    idx[i] = ci[b * NPp + p2img[i]];
  }
  if (i < NPT) atomicAdd(&counts[(size_t)ci[i] * Cc + labels[i]], 1);
}

// ================= weight pre-pack into MFMA B-frag order (+attEff) ========
struct PackDesc { const float* src; short* dst; int K, Nr, nt; };
struct PackArgs { PackDesc d[14]; };

__global__ void k_pack(PackArgs pa,
                       const float* __restrict__ fc1w, const float* __restrict__ fc1b,
                       const float* __restrict__ fc2w, const float* __restrict__ fc2b,
                       const float* __restrict__ fc3w, const float* __restrict__ fc3b,
                       float* __restrict__ attEffs) {
  int stride = gridDim.x * blockDim.x;
  for (int di = 0; di < 14; di++) {
    const float* src = pa.d[di].src;
    short* dst = pa.d[di].dst;
    int K = pa.d[di].K, Nr = pa.d[di].Nr, ntiles = pa.d[di].nt;
    int total = (K / 32) * ntiles * 512;
    for (int idx = blockIdx.x * blockDim.x + threadIdx.x; idx < total; idx += stride) {
      int j = idx & 7, lane = (idx >> 3) & 63, tile = idx >> 9;
      int nt = tile % ntiles, kt = tile / ntiles;
      int k = kt * 32 + (lane >> 4) * 8 + j;
      int n = nt * 16 + (lane & 15);
      float v = (n < Nr) ? src[(size_t)k * Nr + n] : 0.f;
      dst[idx] = f2bf(v);
    }
  }
  if (blockIdx.x < 2 && threadIdx.x < 64) {
    int s = blockIdx.x, t = threadIdx.x;
    const float* f1w = fc1w + s * 64 * 16; const float* f1b = fc1b + s * 16;
    const float* f2w = fc2w + s * 64 * 16; const float* f2b = fc2b + s * 16;
    const float* f3w = fc3w + s * 64;      const float* f3b = fc3b + s * 2;
    float* aE = attEffs + s * 320;
    float p0 = 0.f, p1 = 0.f, v0 = 0.f, v1 = 0.f;
    #pragma unroll
    for (int j = 0; j < 16; j++) {
      p0 = fmaf(f1w[t * 16 + j], f3w[j * 2], p0);
      p1 = fmaf(f1w[t * 16 + j], f3w[j * 2 + 1], p1);
      v0 = fmaf(f2w[t * 16 + j], f3w[(16 + j) * 2], v0);
      v1 = fmaf(f2w[t * 16 + j], f3w[(16 + j) * 2 + 1], v1);
    }
    aE[t * 2] = p0; aE[t * 2 + 1] = p1;
    aE[128 + t * 2] = v0; aE[128 + t * 2 + 1] = v1;
    if (t == 0) {
      float b0 = f3b[0], b1 = f3b[1];
      for (int j = 0; j < 16; j++) {
        b0 += f1b[j] * f3w[j * 2] + f2b[j] * f3w[(16 + j) * 2];
        b1 += f1b[j] * f3w[j * 2 + 1] + f2b[j] * f3w[(16 + j) * 2 + 1];
      }
      aE[256] = b0; aE[257] = b1;
    }
  }
}

// ================= MFMA MLP body: relu(X@W1+b1)@W2+b2 ====================
// Logits land in LDS sL (stride 21); optionally also to global Out.
template<int D>
__device__ __forceinline__ void mfma_mlp_body(const short* sXb, short* sH, float* sL,
    int r0, int rows,
    const short* __restrict__ pw1, const float* __restrict__ B1,
    const short* __restrict__ pw2, const float* __restrict__ B2,
    float* __restrict__ Out) {
  constexpr int LDB = D + 8;
  constexpr int KT1 = D / 32;
  const int t = threadIdx.x;
  const int lane = t & 63, w = t >> 6;
  const int m = lane & 15, quad = lane >> 4;
  const int rowA = 16 * w + m;
  bf16x8 a1[KT1];
  #pragma unroll
  for (int kt = 0; kt < KT1; kt++)
    a1[kt] = *(const bf16x8*)(sXb + rowA * LDB + kt * 32 + quad * 8);
  const bf16x8* b1 = (const bf16x8*)pw1;
  #pragma unroll
  for (int nt = 0; nt < 8; nt++) {
    f32x4 c = {0.f, 0.f, 0.f, 0.f};
    #pragma unroll
    for (int kt = 0; kt < KT1; kt++)
      c = __builtin_amdgcn_mfma_f32_16x16x32_bf16(a1[kt], b1[(kt * 8 + nt) * 64 + lane], c, 0, 0, 0);
    int col = nt * 16 + m;
    float bc = B1[col];
    #pragma unroll
    for (int reg = 0; reg < 4; reg++)
      sH[(16 * w + quad * 4 + reg) * 136 + col] = f2bf(fmaxf(c[reg] + bc, 0.f));
  }
  __syncthreads();
  bf16x8 a2[4];
  #pragma unroll
  for (int kt = 0; kt < 4; kt++)
    a2[kt] = *(const bf16x8*)(sH + rowA * 136 + kt * 32 + quad * 8);
  const bf16x8* b2 = (const bf16x8*)pw2;
  #pragma unroll
  for (int nt = 0; nt < 2; nt++) {
    f32x4 c = {0.f, 0.f, 0.f, 0.f};
    #pragma unroll
    for (int kt = 0; kt < 4; kt++)
      c = __builtin_amdgcn_mfma_f32_16x16x32_bf16(a2[kt], b2[(kt * 2 + nt) * 64 + lane], c, 0, 0, 0);
    int col = nt * 16 + m;
    if (col < Cc) {
      float bc = B2[col];
      #pragma unroll
      for (int reg = 0; reg < 4; reg++) {
        int row16 = 16 * w + quad * 4 + reg;
        float val = c[reg] + bc;
        sL[row16 * 21 + col] = val;
        int gr = r0 + row16;
        if (Out && gr < rows) Out[(size_t)gr * Cc + col] = val;
      }
    }
  }
}

// === fused: pred3d MLP + pts bf16 sidecar + voxlab argmax + CE + E write ===
__global__ void __launch_bounds__(256)
k_mlp_lov_vox(const float* __restrict__ X, uint16_t* __restrict__ pts_bf,
              const short* __restrict__ pw1, const float* __restrict__ B1,
              const short* __restrict__ pw2, const float* __restrict__ B2,
              float* __restrict__ pred3d, int* __restrict__ counts,
              uint16_t* __restrict__ E, float ceScale, float* __restrict__ lossAcc) {
  __shared__ __align__(16) short sXb[64 * 72];
  __shared__ __align__(16) short sH[64 * 136];
  __shared__ float sL[64 * 21];
  int t = threadIdx.x, r0 = blockIdx.x * 64;
  for (int i = t; i < 1024; i += 256) {
    int r = i >> 4, k4 = (i & 15) * 4;
    int gr = r0 + r;
    float4 v = (gr < NV) ? *(const float4*)(X + (size_t)gr * 64 + k4)
                         : make_float4(0.f, 0.f, 0.f, 0.f);
    uint2 p;
    p.x = pk2(v.x, v.y); p.y = pk2(v.z, v.w);
    *(uint2*)(sXb + r * 72 + k4) = p;
    if (gr < NV) *(uint2*)(pts_bf + (size_t)gr * 64 + k4) = p;
  }
  __syncthreads();
  mfma_mlp_body<64>(sXb, sH, sL, r0, NV, pw1, B1, pw2, B2, pred3d);
  __syncthreads();
  if (t < 64) {
    int gr = r0 + t;
    float total = 0.f;
    if (gr < NV) {
      int* crow = counts + (size_t)gr * Cc;
      int best = crow[0], lb = 0;
      crow[0] = 0;
      #pragma unroll
      for (int k = 1; k < Cc; k++) {
        int ck = crow[k]; crow[k] = 0;
        if (ck > best) { best = ck; lb = k; }          // first-max
      }
      const float* l = sL + t * 21;
      float m = l[0];
      #pragma unroll
      for (int c = 1; c < Cc; c++) m = fmaxf(m, l[c]);
      float ex[Cc]; float se = 0.f;
      #pragma unroll
      for (int c = 0; c < Cc; c++) { ex[c] = expf(l[c] - m); se += ex[c]; }
      float inv = 1.f / se, lse = logf(se);
      total = -(l[lb] - m - lse) * ceScale;
      #pragma unroll
      for (int c = 0; c < Cc; c++) {
        float prob = ex[c] * inv;
        int fg = (c == lb) ? 1 : 0;
        float err = fmaxf(fg ? (1.f - prob) : prob, 0.f);
        uint32_t key = __float_as_uint(err) >> 17;
        E[(size_t)c * NV + gr] = (uint16_t)((key << 1) | (uint32_t)fg);
      }
    }
    total = waveReduce(total);
    if (t == 0) atomicAdd(lossAcc, total);
  }
}

// === fused: BN+att fuse -> feats(bf16) + fuse-MLP + CE + KL + E write ======
__global__ void __launch_bounds__(256)
k_fusemlp_lov(const uint16_t* __restrict__ y1, const uint16_t* __restrict__ y2,
              const float* __restrict__ attw, const float* __restrict__ bnpar,
              uint16_t* __restrict__ feats, int s64,
              const short* __restrict__ pw1, const float* __restrict__ B1,
              const short* __restrict__ pw2, const float* __restrict__ B2,
              uint16_t* __restrict__ E, const int* __restrict__ img_label,
              const float* __restrict__ pred3d, const int* __restrict__ idx,
              float ceScale, float klScale, float* __restrict__ lossAcc) {
  __shared__ __align__(16) short sXb[64 * 72];
  __shared__ __align__(16) short sH[64 * 136];
  __shared__ float sL[64 * 21];
  int t = threadIdx.x, r0 = blockIdx.x * 64;
  for (int i = t; i < 1024; i += 256) {
    int r = i >> 4, q = i & 15;
    int gr = r0 + r;
    uint2 zp = make_uint2(0u, 0u);
    if (gr < NIMG) {
      float4 a1 = *(const float4*)(bnpar + q * 4);
      float4 c1 = *(const float4*)(bnpar + 64 + q * 4);
      float4 a2 = *(const float4*)(bnpar + 128 + q * 4);
      float4 c2 = *(const float4*)(bnpar + 192 + q * 4);
      uint2 u1 = *(const uint2*)(y1 + (size_t)gr * 64 + q * 4);
      uint2 u2 = *(const uint2*)(y2 + (size_t)gr * 64 + q * 4);
      float w0 = attw[gr * 2], w1 = attw[gr * 2 + 1];
      float zx = fmaxf(fmaf(bf2f(u1.x & 0xffff), a1.x, c1.x), 0.f) * w0
               + fmaxf(fmaf(bf2f(u2.x & 0xffff), a2.x, c2.x), 0.f) * w1;
      float zy = fmaxf(fmaf(bf2f(u1.x >> 16),   a1.y, c1.y), 0.f) * w0
               + fmaxf(fmaf(bf2f(u2.x >> 16),   a2.y, c2.y), 0.f) * w1;
      float zz = fmaxf(fmaf(bf2f(u1.y & 0xffff), a1.z, c1.z), 0.f) * w0
               + fmaxf(fmaf(bf2f(u2.y & 0xffff), a2.z, c2.z), 0.f) * w1;
      float zw = fmaxf(fmaf(bf2f(u1.y >> 16),   a1.w, c1.w), 0.f) * w0
               + fmaxf(fmaf(bf2f(u2.y >> 16),   a2.w, c2.w), 0.f) * w1;
      zp.x = pk2(zx, zy); zp.y = pk2(zz, zw);
      *(uint2*)(feats + (size_t)gr * 128 + s64 + q * 4) = zp;
    }
    *(uint2*)(sXb + r * 72 + q * 4) = zp;
  }
  __syncthreads();
  mfma_mlp_body<64>(sXb, sH, sL, r0, NIMG, pw1, B1, pw2, B2, nullptr);
  __syncthreads();
  if (t < 64) {
    int gr = r0 + t;
    float total = 0.f;
    if (gr < NIMG) {
      int lb = img_label[gr];
      const float* l = sL + t * 21;
      float m = l[0];
      #pragma unroll
      for (int c = 1; c < Cc; c++) m = fmaxf(m, l[c]);
      float ex[Cc]; float se = 0.f;
      #pragma unroll
      for (int c = 0; c < Cc; c++) { ex[c] = expf(l[c] - m); se += ex[c]; }
      float inv = 1.f / se, lse = logf(se);
      total = -(l[lb] - m - lse) * ceScale;
      #pragma unroll
      for (int c = 0; c < Cc; c++) {
        float prob = ex[c] * inv;
        int fg = (c == lb) ? 1 : 0;
        float err = fmaxf(fg ? (1.f - prob) : prob, 0.f);
        uint32_t key = __float_as_uint(err) >> 17;
        E[(size_t)c * NIMG + gr] = (uint16_t)((key << 1) | (uint32_t)fg);
      }
      // KL(log_softmax(pred3d[idx]) || softmax(fuse_pred)), xlogy form
      const float* q = pred3d + (size_t)idx[gr] * Cc;
      float mq = q[0];
      #pragma unroll
      for (int c = 1; c < Cc; c++) mq = fmaxf(mq, q[c]);
      float sq = 0.f;
      #pragma unroll
      for (int c = 0; c < Cc; c++) sq += expf(q[c] - mq);
      float lsq = logf(sq);
      float kl = 0.f;
      #pragma unroll
      for (int c = 0; c < Cc; c++) {
        float lf = l[c] - m - lse;
        float pf = ex[c] * inv;
        float lq = q[c] - mq - lsq;
        kl += pf * (lf - lq);
      }
      total += kl * klScale;
    }
    total = waveReduce(total);
    if (t == 0) atomicAdd(lossAcc, total);
  }
}

// === fused: final classifier (D=128, bf16 in) + CE + E write ===============
__global__ void __launch_bounds__(256)
k_mlp_lov_img(const uint16_t* __restrict__ Xh,
              const short* __restrict__ pw1, const float* __restrict__ B1,
              const short* __restrict__ pw2, const float* __restrict__ B2,
              uint16_t* __restrict__ E, const int* __restrict__ img_label,
              float ceScale, float* __restrict__ lossAcc) {
  __shared__ __align__(16) short sXb[64 * 136];
  __shared__ __align__(16) short sH[64 * 136];
  __shared__ float sL[64 * 21];
  int t = threadIdx.x, r0 = blockIdx.x * 64;
  for (int i = t; i < 2048; i += 256) {
    int r = i >> 5, k4 = (i & 31) * 4;
    int gr = r0 + r;
    uint2 p = (gr < NIMG) ? *(const uint2*)(Xh + (size_t)gr * 128 + k4) : make_uint2(0u, 0u);
    *(uint2*)(sXb + r * 136 + k4) = p;
  }
  __syncthreads();
  mfma_mlp_body<128>(sXb, sH, sL, r0, NIMG, pw1, B1, pw2, B2, nullptr);
  __syncthreads();
  if (t < 64) {
    int gr = r0 + t;
    float total = 0.f;
    if (gr < NIMG) {
      int lb = img_label[gr];
      const float* l = sL + t * 21;
      float m = l[0];
      #pragma unroll
      for (int c = 1; c < Cc; c++) m = fmaxf(m, l[c]);
      float ex[Cc]; float se = 0.f;
      #pragma unroll
      for (int c = 0; c < Cc; c++) { ex[c] = expf(l[c] - m); se += ex[c]; }
      float inv = 1.f / se, lse = logf(se);
      total = -(l[lb] - m - lse) * ceScale;
      #pragma unroll
      for (int c = 0; c < Cc; c++) {
        float prob = ex[c] * inv;
        int fg = (c == lb) ? 1 : 0;
        float err = fmaxf(fg ? (1.f - prob) : prob, 0.f);
        uint32_t key = __float_as_uint(err) >> 17;
        E[(size_t)c * NIMG + gr] = (uint16_t)((key << 1) | (uint32_t)fg);
      }
    }
    total = waveReduce(total);
    if (t == 0) atomicAdd(lossAcc, total);
  }
}

// ======= fused gather(bf16) + y1/y2 MFMA GEMM + BN-stats + attention =======
__global__ void __launch_bounds__(256)
k_gemm_att(const uint16_t* __restrict__ pts_bf, const int* __restrict__ idx,
           const float* __restrict__ img,
           const short* __restrict__ pc1, const float* __restrict__ c1b,
           const short* __restrict__ pc2, const float* __restrict__ c2b,
           const float* __restrict__ attEff,
           uint16_t* __restrict__ y1, uint16_t* __restrict__ y2,
           float* __restrict__ attw, float* __restrict__ partials) {
  __shared__ __align__(16) short sP[64 * 72], sV[64 * 72];
  __shared__ float sAtt[64 * 8];
  __shared__ float sStat[1024];        // [w][nt][kind][m]
  int t = threadIdx.x;
  int r0 = blockIdx.x * 64;
  for (int i = t; i < 512; i += 256) {  // pts: bf16 rows, 16B per (r,h)
    int r = i >> 3, h = i & 7;
    int gr = r0 + r;
    uint4 p = make_uint4(0u, 0u, 0u, 0u);
    if (gr < NIMG) p = *(const uint4*)(pts_bf + (size_t)idx[gr] * 64 + h * 8);
    *(uint4*)(sP + r * 72 + h * 8) = p;
  }
  for (int i = t; i < 1024; i += 256) { // img: fp32 -> bf16
    int r = i >> 4, q = i & 15;
    int gr = r0 + r;
    float4 vv = make_float4(0.f, 0.f, 0.f, 0.f);
    if (gr < NIMG) vv = *(const float4*)(img + (size_t)gr * 64 + q * 4);
    uint2 qv;
    qv.x = pk2(vv.x, vv.y); qv.y = pk2(vv.z, vv.w);
    *(uint2*)(sV + r * 72 + q * 4) = qv;
  }
  __syncthreads();
  {
    int r = t & 63, qq = t >> 6;
    const float* aP = attEff;
    const float* aV = attEff + 128;
    float l0 = 0.f, l1 = 0.f;
    for (int k = qq * 16; k < qq * 16 + 16; k += 4) {
      uint2 up = *(const uint2*)(sP + r * 72 + k);
      uint2 uv = *(const uint2*)(sV + r * 72 + k);
      float p0 = bf2f(up.x & 0xffff), p1 = bf2f(up.x >> 16);
      float p2 = bf2f(up.y & 0xffff), p3 = bf2f(up.y >> 16);
      float v0 = bf2f(uv.x & 0xffff), v1 = bf2f(uv.x >> 16);
      float v2 = bf2f(uv.y & 0xffff), v3 = bf2f(uv.y >> 16);
      float4 wa = *(const float4*)(aP + 2 * k);
      float4 wb = *(const float4*)(aP + 2 * k + 4);
      l0 += p0 * wa.x + p1 * wa.z + p2 * wb.x + p3 * wb.z;
      l1 += p0 * wa.y + p1 * wa.w + p2 * wb.y + p3 * wb.w;
      float4 ua = *(const float4*)(aV + 2 * k);
      float4 ub = *(const float4*)(aV + 2 * k + 4);
      l0 += v0 * ua.x + v1 * ua.z + v2 * ub.x + v3 * ub.z;
      l1 += v0 * ua.y + v1 * ua.w + v2 * ub.y + v3 * ub.w;
    }
    sAtt[r * 8 + qq * 2] = l0;
    sAtt[r * 8 + qq * 2 + 1] = l1;
  }
  const int lane = t & 63, w = t >> 6;
  const int m = lane & 15, quad = lane >> 4;
  const int rowA = 16 * w + m;
  bf16x8 ap[2], av[2];
  #pragma unroll
  for (int kt = 0; kt < 2; kt++) {
    ap[kt] = *(const bf16x8*)(sP + rowA * 72 + kt * 32 + quad * 8);
    av[kt] = *(const bf16x8*)(sV + rowA * 72 + kt * 32 + quad * 8);
  }
  const bf16x8* b1 = (const bf16x8*)pc1;
  const bf16x8* b2 = (const bf16x8*)pc2;
  #pragma unroll
  for (int nt = 0; nt < 4; nt++) {
    int col = nt * 16 + m;
    f32x4 c1 = {0.f, 0.f, 0.f, 0.f}, c2 = {0.f, 0.f, 0.f, 0.f};
    #pragma unroll
    for (int kt = 0; kt < 2; kt++) {
      c1 = __builtin_amdgcn_mfma_f32_16x16x32_bf16(ap[kt], b1[(kt * 4 + nt) * 64 + lane], c1, 0, 0, 0);
      c2 = __builtin_amdgcn_mfma_f32_16x16x32_bf16(av[kt], b2[(kt * 4 + nt) * 64 + lane], c2, 0, 0, 0);
    }
    float bb1 = c1b[col], bb2 = c2b[col];
    float s1 = 0.f, q1 = 0.f, s2 = 0.f, q2 = 0.f;
    #pragma unroll
    for (int reg = 0; reg < 4; reg++) {
      int gr = r0 + 16 * w + quad * 4 + reg;
      if (gr < NIMG) {
        float v1 = c1[reg] + bb1, v2 = c2[reg] + bb2;
        y1[(size_t)gr * 64 + col] = (uint16_t)f2bf(v1);
        y2[(size_t)gr * 64 + col] = (uint16_t)f2bf(v2);
        s1 += v1; q1 = fmaf(v1, v1, q1);
        s2 += v2; q2 = fmaf(v2, v2, q2);
      }
    }
    s1 += __shfl_down(s1, 32); s1 += __shfl_down(s1, 16);
    q1 += __shfl_down(q1, 32); q1 += __shfl_down(q1, 16);
    s2 += __shfl_down(s2, 32); s2 += __shfl_down(s2, 16);
    q2 += __shfl_down(q2, 32); q2 += __shfl_down(q2, 16);
    if (lane < 16) {
      float* base = sStat + (w * 4 + nt) * 64 + lane;
      base[0]  = s1;
      base[16] = q1;
      base[32] = s2;
      base[48] = q2;
    }
  }
  __syncthreads();
  {
    int kind = t >> 6, col = t & 63;
    int nt = col >> 4, mm = col & 15;
    float v = 0.f;
    #pragma unroll
    for (int ww = 0; ww < 4; ww++)
      v += sStat[(ww * 4 + nt) * 64 + kind * 16 + mm];
    partials[(size_t)blockIdx.x * 256 + kind * 64 + col] = v;
  }
  if (t < 64) {
    int gr = r0 + t;
    if (gr < NIMG) {
      float l0 = attEff[256] + sAtt[t * 8] + sAtt[t * 8 + 2] + sAtt[t * 8 + 4] + sAtt[t * 8 + 6];
      float l1 = attEff[257] + sAtt[t * 8 + 1] + sAtt[t * 8 + 3] + sAtt[t * 8 + 5] + sAtt[t * 8 + 7];
      attw[gr * 2]     = 1.f / (1.f + expf(-l0));
      attw[gr * 2 + 1] = 1.f / (1.f + expf(-l1));
    }
  }
}

// ====== BN partial reduction, stage 1: 64 blocks over 938 rows =============
__global__ void __launch_bounds__(256)
k_colred(const float* __restrict__ partials, int nblk, float* __restrict__ red64) {
  int t = threadIdx.x, j = blockIdx.x;       // 64 blocks
  float v = 0.f;
  for (int b = j; b < nblk; b += 64) v += partials[(size_t)b * 256 + t];
  red64[j * 256 + t] = v;
}

// ====== BN finalize, stage 2: reduce 64x256 + compute bnpar ================
__global__ void __launch_bounds__(1024)
k_colfinal(const float* __restrict__ red64,
           const float* __restrict__ g1, const float* __restrict__ be1,
           const float* __restrict__ g2, const float* __restrict__ be2,
           float* __restrict__ bnpar) {
  __shared__ float red[1024];
  int t = threadIdx.x;
  int slot = t & 255, part = t >> 8;
  float v = 0.f;
  for (int b = part; b < 64; b += 4) v += red64[b * 256 + slot];
  red[part * 256 + slot] = v;
  __syncthreads();
  if (t < 256) red[t] = red[t] + red[256 + t] + red[512 + t] + red[768 + t];
  __syncthreads();
  if (t < 64) {
    float n = (float)NIMG;
    float mu1 = red[t] / n;
    float var1 = red[64 + t] / n - mu1 * mu1;
    float a1 = g1[t] / sqrtf(var1 + BN_EPS);
    bnpar[t] = a1; bnpar[64 + t] = be1[t] - mu1 * a1;
    float mu2 = red[128 + t] / n;
    float var2 = red[192 + t] / n - mu2 * mu2;
    float a2 = g2[t] / sqrtf(var2 + BN_EPS);
    bnpar[128 + t] = a2; bnpar[192 + t] = be2[t] - mu2 * a2;
  }
}

// ================= LDS-privatized histogram (count|fg) =====================
__global__ void __launch_bounds__(1024)
k_lov_hist2(const uint16_t* __restrict__ E, int n,
            uint32_t* __restrict__ H, uint32_t* __restrict__ HF) {
  __shared__ uint32_t lcf[NB];
  int t = threadIdx.x;
  int cls = blockIdx.x / NCH, ch = blockIdx.x - cls * NCH;
  int CHsz = (n + NCH - 1) / NCH;
  int i0 = ch * CHsz;
  int i1 = min(n, i0 + CHsz);
  for (int b = t; b < NB; b += 1024) lcf[b] = 0u;
  __syncthreads();
  const uint16_t* Ec = E + (size_t)cls * n;
  for (int i = i0 + t; i < i1; i += 1024) {
    uint32_t p = Ec[i];
    atomicAdd(&lcf[p >> 1], 0x10000u | (p & 1u));    // count hi16, fg lo16
  }
  __syncthreads();
  uint32_t* Hc  = H  + (size_t)cls * NB;
  uint32_t* HFc = HF + (size_t)cls * NB;
  for (int b = t; b < NB; b += 1024) {
    uint32_t v = lcf[b];
    if (v) {
      atomicAdd(&Hc[b], v >> 16);
      uint32_t f = v & 0xFFFFu;
      if (f) atomicAdd(&HFc[b], f);
    }
  }
}

// ================= Lovász scan+bin (per class; self-cleaning; slotted) =====
__global__ void __launch_bounds__(256)
k_lov_scanbin(uint32_t* __restrict__ H, uint32_t* __restrict__ HF, int n,
              int call, float* __restrict__ lossesC5, int* __restrict__ gts5) {
  __shared__ uint32_t lc[256 * 17], lf[256 * 17];
  __shared__ int sC[256], sF[256];
  __shared__ float sRed[4];
  int cls = blockIdx.x, t = threadIdx.x;
  uint32_t* Hc  = H  + (size_t)cls * NB;
  uint32_t* HFc = HF + (size_t)cls * NB;
  int fsum = 0;
  for (int i = t; i < NB; i += 256) fsum += (int)HFc[i];
  fsum = waveReduceI(fsum);
  if ((t & 63) == 0) sC[t >> 6] = fsum;
  __syncthreads();
  int Ftot = sC[0] + sC[1] + sC[2] + sC[3];
  __syncthreads();
  float gts = (float)Ftot;
  float contribSum = 0.f;
  int carryC = 0, carryF = 0;
  for (int ph = 0; ph < 2; ph++) {
    int base = ph * 4096;
    for (int i = t; i < 4096; i += 256) {
      int row = i >> 4, col = i & 15;
      lc[row * 17 + col] = Hc[base + i];  Hc[base + i] = 0u;   // self-clean
      lf[row * 17 + col] = HFc[base + i]; HFc[base + i] = 0u;
    }
    __syncthreads();
    int locC = 0, locF = 0;
    #pragma unroll
    for (int j = 0; j < 16; j++) { locC += (int)lc[t * 17 + j]; locF += (int)lf[t * 17 + j]; }
    sC[t] = locC; sF[t] = locF;
    __syncthreads();
    for (int o = 1; o < 256; o <<= 1) {
      int a = (t >= o) ? sC[t - o] : 0;
      int b = (t >= o) ? sF[t - o] : 0;
      __syncthreads();
      sC[t] += a; sF[t] += b;
      __syncthreads();
    }
    int runC = carryC + sC[t] - locC;
    int runF = carryF + sF[t] - locF;
    int phTotC = sC[255], phTotF = sF[255];
    #pragma unroll
    for (int j = 0; j < 16; j++) {
      int cnt = (int)lc[t * 17 + j];
      int fgc = (int)lf[t * 17 + j];
      runC += cnt; runF += fgc;
      if (cnt > 0 && Ftot > 0) {
        float r0 = (float)(n - runC);
        float F0 = (float)(Ftot - runF);
        float r1 = r0 + (float)cnt;
        float F1 = F0 + (float)fgc;
        float emean = __uint_as_float((uint32_t)(base + t * 16 + j) << 17);  // bin edge
        float J1 = r1 / (gts + r1 - F1);
        float J0 = r0 / (gts + r0 - F0);
        contribSum += emean * (J1 - J0);
      }
    }
    carryC += phTotC; carryF += phTotF;
    __syncthreads();
  }
  contribSum = waveReduce(contribSum);
  if ((t & 63) == 0) sRed[t >> 6] = contribSum;
  __syncthreads();
  if (t == 0) {
    lossesC5[call * 32 + cls] = (Ftot > 0) ? (sRed[0] + sRed[1] + sRed[2] + sRed[3]) : 0.f;
    gts5[call * 32 + cls] = Ftot;
  }
}

// ================= final: fold 5 lovasz combines + output ==================
__global__ void k_final(const float* __restrict__ lossAcc,
                        const float* __restrict__ lossesC5, const int* __restrict__ gts5,
                        float* __restrict__ out) {
  const float coefs[5] = {1.0f, 0.5f, 1.0f, 0.5f, 1.0f};
  float loss = lossAcc[0];
  for (int call = 0; call < 5; call++) {
    float s = 0.f; int np = 0;
    for (int c = 0; c < Cc; c++)
      if (gts5[call * 32 + c] > 0) { s += lossesC5[call * 32 + c]; np++; }
    loss += coefs[call] * s / (float)(np > 0 ? np : 1);
  }
  out[0] = loss;
}

extern "C" void kernel_launch(void* const* d_in, const int* in_sizes, int n_in,
                              void* d_out, int out_size, void* d_ws, size_t ws_size,
                              hipStream_t stream) {
  const float* img_feat = (const float*)d_in[0];
  const float* pts_feat = (const float*)d_in[1];
  const int* coors_inv  = (const int*)d_in[2];
  const int* labels     = (const int*)d_in[3];
  const int* img_label  = (const int*)d_in[4];
  const int* p2img      = (const int*)d_in[5];
  const float* w3a = (const float*)d_in[6];
  const float* b3a = (const float*)d_in[7];
  const float* w3b = (const float*)d_in[8];
  const float* b3b = (const float*)d_in[9];
  const float* wfa = (const float*)d_in[10];
  const float* bfa = (const float*)d_in[11];
  const float* wfb = (const float*)d_in[12];
  const float* bfb = (const float*)d_in[13];
  const float* fc1w = (const float*)d_in[14];
  const float* fc1b = (const float*)d_in[15];
  const float* fc2w = (const float*)d_in[16];
  const float* fc2b = (const float*)d_in[17];
  const float* fc3w = (const float*)d_in[18];
  const float* fc3b = (const float*)d_in[19];
  const float* c1w  = (const float*)d_in[20];
  const float* c1b  = (const float*)d_in[21];
  const float* bn1g = (const float*)d_in[22];
  const float* bn1b = (const float*)d_in[23];
  const float* c2w  = (const float*)d_in[24];
  const float* c2b  = (const float*)d_in[25];
  const float* bn2g = (const float*)d_in[26];
  const float* bn2b = (const float*)d_in[27];
  const float* clw1 = (const float*)d_in[28];
  const float* clb1 = (const float*)d_in[29];
  const float* clw2 = (const float*)d_in[30];
  const float* clb2 = (const float*)d_in[31];
  (void)in_sizes; (void)n_in; (void)out_size; (void)ws_size;

  // ---- workspace layout ----
  char* ws = (char*)d_ws;
  size_t off = 0;
  auto alloc = [&](size_t bytes) { void* p = ws + off; off += (bytes + 255) & ~(size_t)255; return p; };
  uint16_t* feats = (uint16_t*)alloc((size_t)NIMG * 128 * 2);  // persistent, bf16
  float* pred3d = (float*)alloc((size_t)NV * Cc * 4);
  int*   idx    = (int*)  alloc((size_t)NIMG * 4);
  uint16_t* pts_bf = (uint16_t*)alloc((size_t)NV * Hh * 2);    // bf16 pts sidecar
  uint16_t* y1 = (uint16_t*)alloc((size_t)NIMG * Hh * 2);
  uint16_t* y2 = (uint16_t*)alloc((size_t)NIMG * Hh * 2);
  uint16_t* E  = (uint16_t*)alloc((size_t)Cc * NV * 2);        // packed bin-key|fg
  float* partials = (float*)alloc((size_t)NBLK_GA * 256 * 4);  // BN stat partials
  float* red64    = (float*)alloc(64 * 256 * 4);
  float* attw     = (float*)alloc((size_t)NIMG * 2 * 4);
  short* pwAll = (short*)alloc(86016 * 2);                     // packed bf16 weights
  short* pw3a0 = pwAll,          * pw3a1 = pwAll + 8192;
  short* pwfa0 = pwAll + 16384,  * pwfa1 = pwAll + 24576;
  short* pw3b0 = pwAll + 32768,  * pw3b1 = pwAll + 36864;
  short* pwfb0 = pwAll + 40960,  * pwfb1 = pwAll + 45056;
  short* pcl1  = pwAll + 49152;
  short* pcl2  = pwAll + 65536;
  short* pc1w0 = pwAll + 69632,  * pc1w1 = pwAll + 73728;
  short* pc2w0 = pwAll + 77824,  * pc2w1 = pwAll + 81920;
  // zero region: H | HF | counts | statsF  (ONE memset)
  size_t zbytes = (size_t)2 * Cc * NB * 4 + (size_t)NV * Cc * 4 + 8192;
  uint32_t* H  = (uint32_t*)alloc(zbytes);
  uint32_t* HF = H + (size_t)Cc * NB;
  int*   counts = (int*)(H + (size_t)2 * Cc * NB);
  float* statsF = (float*)((char*)counts + (size_t)NV * Cc * 4);
  float* lossAcc  = statsF;               // [0]
  float* lossesC5 = statsF + 32;          // 5*32
  int*   gts5     = (int*)(statsF + 192); // 5*32 ints
  float* bnpar    = statsF + 384;         // 256 floats
  float* attEffs  = statsF + 640;         // 2*320 floats

  hipMemsetAsync(H, 0, zbytes, stream);   // counts/statsF self-clean or overwritten later

  PackArgs pa;
  pa.d[0]  = {w3a,        pw3a0, 64, 128, 8};
  pa.d[1]  = {w3a + 8192, pw3a1, 64, 128, 8};
  pa.d[2]  = {wfa,        pwfa0, 64, 128, 8};
  pa.d[3]  = {wfa + 8192, pwfa1, 64, 128, 8};
  pa.d[4]  = {w3b,        pw3b0, 128, 20, 2};
  pa.d[5]  = {w3b + 2560, pw3b1, 128, 20, 2};
  pa.d[6]  = {wfb,        pwfb0, 128, 20, 2};
  pa.d[7]  = {wfb + 2560, pwfb1, 128, 20, 2};
  pa.d[8]  = {clw1,       pcl1, 128, 128, 8};
  pa.d[9]  = {clw2,       pcl2, 128, 20, 2};
  pa.d[10] = {c1w,        pc1w0, 64, 64, 4};
  pa.d[11] = {c1w + 4096, pc1w1, 64, 64, 4};
  pa.d[12] = {c2w,        pc2w0, 64, 64, 4};
  pa.d[13] = {c2w + 4096, pc2w1, 64, 64, 4};
  k_pack<<<128, 256, 0, stream>>>(pa, fc1w, fc1b, fc2w, fc2b, fc3w, fc3b, attEffs);

  int call = 0;
  for (int s = 0; s < 2; s++) {
    const float* pf_s = pts_feat + (size_t)s * NV * Hh;
    const float* if_s = img_feat + (size_t)s * NIMG * Hh;
    const int*   ci_s = coors_inv + (size_t)s * NPT;
    short* pw1 = s ? pw3a1 : pw3a0;
    short* pw2 = s ? pw3b1 : pw3b0;
    short* pf1 = s ? pwfa1 : pwfa0;
    short* pf2 = s ? pwfb1 : pwfb0;
    short* pc1 = s ? pc1w1 : pc1w0;
    short* pc2 = s ? pc2w1 : pc2w0;
    // voxel vote + gather idx (fused; counts must be ready before MLP)
    k_counts_idx<<<(NPT + 255) / 256, 256, 0, stream>>>(ci_s, labels, counts, p2img, idx);
    // pred3d MLP + pts_bf sidecar + fused voxlab-argmax (self-clean) + CE + E
    k_mlp_lov_vox<<<NV / 64, 256, 0, stream>>>(pf_s, pts_bf,
        pw1, b3a + s * 128, pw2, b3b + s * Cc, pred3d, counts, E, 1.0f / NV, lossAcc);
    k_lov_hist2<<<Cc * NCH, 1024, 0, stream>>>(E, NV, H, HF);
    k_lov_scanbin<<<Cc, 256, 0, stream>>>(H, HF, NV, call++, lossesC5, gts5);
    // fused gather(bf16) + MFMA GEMM + atomic-free stats + linear attention
    k_gemm_att<<<NBLK_GA, 256, 0, stream>>>(pts_bf, idx, if_s,
        pc1, c1b + s * 64, pc2, c2b + s * 64, attEffs + s * 320, y1, y2, attw, partials);
    k_colred<<<64, 256, 0, stream>>>(partials, NBLK_GA, red64);
    k_colfinal<<<1, 1024, 0, stream>>>(red64, bn1g + s * 64, bn1b + s * 64,
                                       bn2g + s * 64, bn2b + s * 64, bnpar);
    // fuse -> feats(bf16) + fuse MLP + fused CE+KL+E (no fusepred global)
    k_fusemlp_lov<<<NBLK_GA, 256, 0, stream>>>(y1, y2, attw, bnpar, feats, s * 64,
        pf1, bfa + s * 128, pf2, bfb + s * Cc, E, img_label, pred3d, idx,
        0.5f / NIMG, 0.025f / ((float)NIMG * Cc), lossAcc);
    k_lov_hist2<<<Cc * NCH, 1024, 0, stream>>>(E, NIMG, H, HF);
    k_lov_scanbin<<<Cc, 256, 0, stream>>>(H, HF, NIMG, call++, lossesC5, gts5);
  }
  // final classifier on concat feats + fused CE + E
  k_mlp_lov_img<<<NBLK_GA, 256, 0, stream>>>(feats, pcl1, clb1, pcl2, clb2,
      E, img_label, 1.0f / NIMG, lossAcc);
  k_lov_hist2<<<Cc * NCH, 1024, 0, stream>>>(E, NIMG, H, HF);
  k_lov_scanbin<<<Cc, 256, 0, stream>>>(H, HF, NIMG, call++, lossesC5, gts5);
  k_final<<<1, 1, 0, stream>>>(lossAcc, lossesC5, gts5, (float*)d_out);
}